// Round 12
// baseline (51.535 us; speedup 1.0000x reference)
//
#include <hip/hip_runtime.h>
#include <hip/hip_bf16.h>
#include <stdint.h>

// RefBasedDeepMetric: out[b] = ||x_b@W + b||^2 + mean_r||refs_r@W + b||^2 - 2*(x_b@W + b).t
// with t = mean_r(vrefs).  Two row-norm-reduced 4096x1024x1024 GEMMs, fused epilogues.
// R7: XCD co-location. R9: f32 A staged direct (cvt_pk). R10: tvec->MFMA fold. R11: gated
// t-MFMA + counted vmcnt(6). 44.6us.
// R12: SPLIT refs/x GEMMs into two kernels. t = column-mean of refs-GEMM output,
//      accumulated by refs-kernel epilogue (tcol atomics) — colsum machinery + k_tvec
//      + prep refs-read ALL gone. x-kernel writes out directly; dedicated ms-block
//      (bx=256) folds mean_sq_ref in — k_tail gone. 3 launches / 2 gaps (was 4/3).

typedef __attribute__((ext_vector_type(8))) short short8;
typedef __attribute__((ext_vector_type(4))) float f32x4;

__device__ __forceinline__ short f2bf(float f) {
  uint32_t u = __builtin_bit_cast(uint32_t, f);
  uint32_t r = (u + 0x7fffu + ((u >> 16) & 1u)) >> 16;  // RNE
  return (short)r;
}

// ---- workspace layout (bytes) ----
#define WS_WT 0u          // W^T bf16   2097152
#define WS_TC 2097152u    // tcol f32   4096   (sum over rows of vrefs, incl. bias)
#define WS_RR 2101248u    // refrow f32 16384

// ---- prep: W transpose->bf16, zero {out, refrow, tcol} ----
// blocks [0,256): transpose;  [256,260): zeroing (runs every replay).
__global__ __launch_bounds__(256) void k_prep(
    const float* __restrict__ W, short* __restrict__ wt,
    float* __restrict__ tcol, float* __restrict__ refrow, float* __restrict__ out) {
  __shared__ short tile[64][68];
  const int b = blockIdx.x, t = threadIdx.x;
  if (b < 256) {
    const int tk = (b >> 4) * 64, tn = (b & 15) * 64;
    const int kk = t >> 4, nn4 = (t & 15) * 4;
#pragma unroll
    for (int p = 0; p < 4; ++p) {
      int k = kk + p * 16;
      float4 v = *(const float4*)&W[(size_t)(tk + k) * 1024 + tn + nn4];
      tile[nn4 + 0][k] = f2bf(v.x);
      tile[nn4 + 1][k] = f2bf(v.y);
      tile[nn4 + 2][k] = f2bf(v.z);
      tile[nn4 + 3][k] = f2bf(v.w);
    }
    __syncthreads();
    const int nn = t >> 4, kk4 = (t & 15) * 4;
#pragma unroll
    for (int p = 0; p < 4; ++p) {
      int n = nn + p * 16;
      uint32_t lo = (uint16_t)tile[n][kk4 + 0] | ((uint32_t)(uint16_t)tile[n][kk4 + 1] << 16);
      uint32_t hi = (uint16_t)tile[n][kk4 + 2] | ((uint32_t)(uint16_t)tile[n][kk4 + 3] << 16);
      *(uint2*)&wt[(size_t)(tn + n) * 1024 + tk + kk4] = make_uint2(lo, hi);
    }
  } else {
    const int i = (b - 256) * 256 + t;     // 0..1023
    const float4 z = make_float4(0.f, 0.f, 0.f, 0.f);
    ((float4*)out)[i] = z;                 // out: 1024 float4
    ((float4*)refrow)[i] = z;              // refrow: 1024 float4
    if (i < 256) ((float4*)tcol)[i] = z;   // tcol: 256 float4
  }
}

// ---- GEMM kernel (templated on which half) ----
// 128x128 tile, BK=64, 512 thr / 8 waves (2x4), depth-2, counted vmcnt(6).
// A from f32 (reg-staged, cvt_pk, swizzled ds_write); B via global_load_lds.
// mt = bx&31, nt = bx>>5  ->  bx%8 = mt%8: same-A blocks co-located per XCD.
// IS_X==false: epilogue -> refrow (row ||v||^2) + tcol (column sums of v).
// IS_X==true : epilogue -> out atomicAdd(sq - 2*v.t);  block 256 = ms-finalizer.
template <bool IS_X>
__global__ __launch_bounds__(512, 4) void k_gemm(
    const float* __restrict__ Am, const short* __restrict__ Wt,
    const float* __restrict__ bias, float* __restrict__ tcol,
    float* __restrict__ refrow, float* __restrict__ out) {
  __shared__ __align__(16) short As[2][128 * 64];
  __shared__ __align__(16) short Bs[2][128 * 64];
  const int t = threadIdx.x;
  const int w = t >> 6, l = t & 63;

  if (IS_X && blockIdx.x >= 256) {
    // ms-finalizer: refrow is complete (written by the previous kernel).
    __shared__ float sh[8];
    float s = 0.f;
    for (int i = t; i < 4096; i += 512) s += refrow[i];
#pragma unroll
    for (int off = 32; off; off >>= 1) s += __shfl_down(s, off, 64);
    if (l == 0) sh[w] = s;
    __syncthreads();
    if (t == 0) {
      float tot = 0.f;
#pragma unroll
      for (int i = 0; i < 8; ++i) tot += sh[i];
      sh[0] = tot * (1.0f / 4096.0f);
    }
    __syncthreads();
    const float ms = sh[0];
    for (int i = t; i < 4096; i += 512) atomicAdd(&out[i], ms);
    return;
  }

  const int wr = w >> 2, wc = w & 3;       // 2x4 wave grid; wave tile 64 rows x 32 cols
  const int bx = blockIdx.x;
  const int mt = bx & 31;                  // 0..31
  const int nt = bx >> 5;                  // 0..7
  const int m0 = mt * 128;
  const int n0 = nt * 128;

  const int srow = t >> 3;   // 0..63   (B staging)
  const int sslot = t & 7;
  const int arow = t >> 4;   // 0..31   (A staging: 32 rows x 64 f32 per issue)
  const int acol = (t & 15) * 4;
  const int asl = (t & 15) >> 1, ah = t & 1;

  f32x4 acc[4][2] = {};
  float4 areg[4];

  auto stageB = [&](int buf, int kt) {
    const int k0 = kt * 64;
#pragma unroll
    for (int issue = 0; issue < 2; ++issue) {
      const int row = srow + issue * 64;
      const int sg = sslot ^ (row & 7);  // pre-swizzled global source (rule #21)
      const short* gb = Wt + ((size_t)(n0 + row) * 1024 + k0 + sg * 8);
      char* lb = (char*)&Bs[buf][0] + issue * 8192 + w * 1024;
      __builtin_amdgcn_global_load_lds(
          (const __attribute__((address_space(1))) unsigned int*)gb,
          (__attribute__((address_space(3))) unsigned int*)lb, 16, 0, 0);
    }
  };
  auto loadA = [&](int kt) {
    const int k0 = kt * 64;
#pragma unroll
    for (int i = 0; i < 4; ++i) {
      const int r = arow + i * 32;
      areg[i] = *(const float4*)&Am[(size_t)(m0 + r) * 1024 + k0 + acol];
    }
  };
  auto writeA = [&](int buf) {
#pragma unroll
    for (int i = 0; i < 4; ++i) {
      const int r = arow + i * 32;
      uint32_t lo, hi;
      asm("v_cvt_pk_bf16_f32 %0, %1, %2" : "=v"(lo) : "v"(areg[i].x), "v"(areg[i].y));
      asm("v_cvt_pk_bf16_f32 %0, %1, %2" : "=v"(hi) : "v"(areg[i].z), "v"(areg[i].w));
      char* p = (char*)&As[buf][0] + r * 128 + (((asl ^ (r & 7)) * 16) + ah * 8);
      *(uint2*)p = make_uint2(lo, hi);
    }
  };

  // prologue: loadA(0) first so writeA(0)'s implicit wait drains only A(0).
  loadA(0);
  stageB(0, 0);
  stageB(1, 1);
  writeA(0);
  loadA(1);

  // K-loop (R11 schedule): steady queue at top = {B(kt):2, A(kt+1):4, B(kt+1):2}
  // -> vmcnt(6) drains exactly B(kt); lgkmcnt(0) drains own ds_writes.
  for (int kt = 0; kt < 16; ++kt) {
    if (kt < 15) asm volatile("s_waitcnt vmcnt(6) lgkmcnt(0)" ::: "memory");
    else         asm volatile("s_waitcnt vmcnt(0) lgkmcnt(0)" ::: "memory");
    __builtin_amdgcn_s_barrier();
    const int cur = kt & 1;
    if (kt + 1 < 16) writeA((kt + 1) & 1);   // As[cur^1] read-free since prev barrier2
    if (kt + 2 < 16) loadA(kt + 2);
#pragma unroll
    for (int kk = 0; kk < 2; ++kk) {
      short8 af[4], bfr[2];
#pragma unroll
      for (int i = 0; i < 4; ++i) {
        const int ra = wr * 64 + i * 16 + (l & 15);
        const int s = (l >> 4) + kk * 4;
        af[i] = *(const short8*)&As[cur][ra * 64 + ((s ^ (ra & 7)) * 8)];
      }
#pragma unroll
      for (int j = 0; j < 2; ++j) {
        const int rbw = wc * 32 + j * 16 + (l & 15);
        const int s = (l >> 4) + kk * 4;
        bfr[j] = *(const short8*)&Bs[cur][rbw * 64 + ((s ^ (rbw & 7)) * 8)];
      }
      __builtin_amdgcn_s_setprio(1);
#pragma unroll
      for (int i = 0; i < 4; ++i)
#pragma unroll
        for (int j = 0; j < 2; ++j)
          acc[i][j] = __builtin_amdgcn_mfma_f32_16x16x32_bf16(af[i], bfr[j], acc[i][j], 0, 0, 0);
      __builtin_amdgcn_s_setprio(0);
    }
    __builtin_amdgcn_s_barrier();
    if (kt + 2 < 16) stageB(cur, kt + 2);
  }

  // ---- epilogue ----
  float bv[2];
#pragma unroll
  for (int n2 = 0; n2 < 2; ++n2) bv[n2] = bias[n0 + wc * 32 + n2 * 16 + (l & 15)];

  if (IS_X) {
    float tvv[2];
#pragma unroll
    for (int n2 = 0; n2 < 2; ++n2)
      tvv[n2] = tcol[n0 + wc * 32 + n2 * 16 + (l & 15)] * (1.0f / 4096.0f);
#pragma unroll
    for (int m4 = 0; m4 < 4; ++m4) {
#pragma unroll
      for (int j = 0; j < 4; ++j) {
        float sq = 0.f, cr = 0.f;
#pragma unroll
        for (int n2 = 0; n2 < 2; ++n2) {
          const float v = acc[m4][n2][j] + bv[n2];
          sq += v * v;
          cr += v * tvv[n2];
        }
        float comb = sq - 2.0f * cr;
#pragma unroll
        for (int off = 1; off < 16; off <<= 1) comb += __shfl_xor(comb, off, 64);
        if ((l & 15) == 0) {
          const int rm = m0 + wr * 64 + m4 * 16 + (l >> 4) * 4 + j;
          atomicAdd(&out[rm], comb);
        }
      }
    }
  } else {
    // row norms -> refrow
#pragma unroll
    for (int m4 = 0; m4 < 4; ++m4) {
#pragma unroll
      for (int j = 0; j < 4; ++j) {
        float sq = 0.f;
#pragma unroll
        for (int n2 = 0; n2 < 2; ++n2) {
          const float v = acc[m4][n2][j] + bv[n2];
          sq += v * v;
        }
#pragma unroll
        for (int off = 1; off < 16; off <<= 1) sq += __shfl_xor(sq, off, 64);
        if ((l & 15) == 0) {
          const int rm = m0 + wr * 64 + m4 * 16 + (l >> 4) * 4 + j;
          atomicAdd(&refrow[rm], sq);
        }
      }
    }
    // column sums (incl. bias) -> tcol: this thread covers 16 rows of its 2 columns
#pragma unroll
    for (int n2 = 0; n2 < 2; ++n2) {
      float cs = 16.0f * bv[n2];
#pragma unroll
      for (int m4 = 0; m4 < 4; ++m4)
#pragma unroll
        for (int j = 0; j < 4; ++j) cs += acc[m4][n2][j];
      cs += __shfl_xor(cs, 16, 64);   // sum the 4 row-groups (l>>4)
      cs += __shfl_xor(cs, 32, 64);
      if ((l >> 4) == 0)
        atomicAdd(&tcol[n0 + wc * 32 + n2 * 16 + (l & 15)], cs);
    }
  }
}

extern "C" void kernel_launch(void* const* d_in, const int* in_sizes, int n_in,
                              void* d_out, int out_size, void* d_ws, size_t ws_size,
                              hipStream_t stream) {
  const float* x    = (const float*)d_in[0];
  const float* refs = (const float*)d_in[1];
  const float* W    = (const float*)d_in[2];
  const float* bias = (const float*)d_in[3];
  float* out = (float*)d_out;
  char* ws = (char*)d_ws;

  short* wt     = (short*)(ws + WS_WT);
  float* tcol   = (float*)(ws + WS_TC);
  float* refrow = (float*)(ws + WS_RR);

  hipLaunchKernelGGL(k_prep, dim3(260), dim3(256), 0, stream, W, wt, tcol, refrow, out);
  hipLaunchKernelGGL(k_gemm<false>, dim3(256), dim3(512), 0, stream,
                     refs, wt, bias, tcol, refrow, out);
  hipLaunchKernelGGL(k_gemm<true>, dim3(257), dim3(512), 0, stream,
                     x, wt, bias, tcol, refrow, out);
}